// Round 3
// baseline (387.946 us; speedup 1.0000x reference)
//
#include <hip/hip_runtime.h>
#include <hip/hip_cooperative_groups.h>
#include <math.h>

namespace cg = cooperative_groups;

// Problem constants
#define CIMG  1024
#define H1F   512
#define H2F   256
#define NODE  2048

// Workspace layout (float offsets) — every element written before read.
#define OFF_H1P  0        // h1part [32][8][512]  = 131072
#define OFF_H2P  131072   // h2part [16][8][256]  = 32768
#define OFF_XP   163840   // xpart  [4][8][2048]  = 65536
#define OFF_Y2P  229376   // y2part [2][8][128][4]= 8192
#define OFF_EW   237568   // ew     [56][128]     = 7168
#define OFF_DX   244736   // dotxr  [dotb:2*8*4][xr:2*8*4] = 128

// ---------------------------------------------------------------------------
// One cooperative kernel, 256 blocks x 256 threads, 4 grid syncs.
//   Stage A: blocks 0..63  L1 split-K partials (kc=b>>1 of K=32, cc=b&1)
//            block 64      full edge path -> ew[56][128]
//   Stage B: blocks 0..15  L2 (sum 32 h1 partials, kchunk=32 over K=512)
//   Stage C: blocks 0..31  L3 (sum 16 h2 partials, kc=b>>3, cc=b&7)
//   Stage D: all 256       Y2 partials (t=b>>1, half=b&1); blocks t==0 also
//                          compute dotb = x·pb2view, xr = x·root per half
//   Stage E: block 0       edge messages + combine -> out[8][4]
// ---------------------------------------------------------------------------
__global__ __launch_bounds__(256) void coop_all(
    const float* __restrict__ roi,
    const float* __restrict__ bbox, const float* __restrict__ dirs,
    const float* __restrict__ pri,
    const float* __restrict__ ncp_w1, const float* __restrict__ ncp_b1,
    const float* __restrict__ ncp_w2, const float* __restrict__ ncp_b2,
    const float* __restrict__ ncp_w3, const float* __restrict__ ncp_b3,
    const float* __restrict__ ep_w1, const float* __restrict__ ep_b1,
    const float* __restrict__ ep_w2, const float* __restrict__ ep_b2,
    const float* __restrict__ ep_w3, const float* __restrict__ ep_b3,
    const float* __restrict__ pr_w1, const float* __restrict__ pr_b1,
    const float* __restrict__ pr_w2, const float* __restrict__ pr_b2,
    const float* __restrict__ root, const float* __restrict__ bias,
    float* __restrict__ h1part, float* __restrict__ h2part,
    float* __restrict__ xpart, float* __restrict__ y2part,
    float* __restrict__ ewbuf, float* __restrict__ dotxr,
    float* __restrict__ out)
{
    cg::grid_group grid = cg::this_grid();
    __shared__ float smem[8320];   // stage D needs 8192+128; edge needs 2848
    const int b = blockIdx.x;
    const int tid = threadIdx.x;
    const int lane = tid & 63, wave = tid >> 6;

    // ======================= Stage A =======================
    if (b < 64) {
        // L1 split-K: kc = b>>1 (32 kchunks of 32), cc = b&1 (256 cols)
        const int kc = b >> 1;
        const int kbeg = kc * 32;
        const int cbase = (b & 1) * 256;
        {
            int r = tid >> 5, kk = tid & 31;
            smem[tid] = roi[r * CIMG + kbeg + kk];   // xin[8][32]
        }
        __syncthreads();
        const int c = cbase + tid;
        float acc[8] = {0, 0, 0, 0, 0, 0, 0, 0};
        const float* Wp = ncp_w1 + (size_t)kbeg * H1F + c;
#pragma unroll 8
        for (int kk = 0; kk < 32; ++kk) {
            float w = Wp[(size_t)kk * H1F];
#pragma unroll
            for (int r = 0; r < 8; ++r) acc[r] += smem[r * 32 + kk] * w;
        }
        float* outp = h1part + kc * 4096;
#pragma unroll
        for (int r = 0; r < 8; ++r) outp[r * H1F + c] = acc[r];
    } else if (b == 64) {
        // ---- edge path ----
        float* attr = smem;            // [8][8]   = 64
        float* g1   = smem + 64;       // [8][256] = 2048
        float* g2   = smem + 2112;     // [8][64]  = 512
        float* ebuf = smem + 2624;     // [56][4]  = 224
        if (tid < 64) {
            int r = tid >> 3, j = tid & 7;
            attr[r * 8 + j] = (j < 4) ? bbox[r * 4 + j] * (1.0f / 1024.0f)
                                      : dirs[r * 4 + (j - 4)];
        }
        __syncthreads();
        {
            int cc = tid;
            for (int r = 0; r < 8; ++r) {
                float s = ep_b1[cc];
#pragma unroll
                for (int j = 0; j < 8; ++j) s += attr[r * 8 + j] * ep_w1[j * 256 + cc];
                g1[r * 256 + cc] = s > 0.f ? s : 0.f;
            }
        }
        __syncthreads();
        for (int idx = tid; idx < 512; idx += 256) {
            int r = idx >> 6, cc = idx & 63;
            float s = ep_b2[cc];
            for (int j = 0; j < 256; ++j) s += g1[r * 256 + j] * ep_w2[j * 64 + cc];
            g2[idx] = s > 0.f ? s : 0.f;
        }
        __syncthreads();
        if (tid < 168) {   // g3 flat [8*21] == e channels 0..2 flat [56*3]
            int r = tid / 21, q = tid % 21;
            float s = ep_b3[q];
            for (int j = 0; j < 64; ++j) s += g2[r * 64 + j] * ep_w3[j * 21 + q];
            ebuf[(tid / 3) * 4 + (tid % 3)] = 1.f / (1.f + expf(-s));
        }
        if (tid < 56) {    // HigherPri quirk: pri[e/7] > pri[e%7]
            ebuf[tid * 4 + 3] = (pri[tid / 7] > pri[tid % 7]) ? 1.f : 0.f;
        }
        __syncthreads();
        for (int idx = tid; idx < 56 * 128; idx += 256) {
            int e = idx >> 7, t = idx & 127;
            float s = pr_b1[t];
#pragma unroll
            for (int ch = 0; ch < 4; ++ch) s += ebuf[e * 4 + ch] * pr_w1[ch * 128 + t];
            ewbuf[idx] = s > 0.f ? s : 0.f;
        }
    }
    grid.sync();

    // ======================= Stage B: L2 =======================
    if (b < 16) {
        const int kbeg = b * 32;
        {
            int r = tid >> 5, kk = tid & 31;
            int k = kbeg + kk;
            float v = ncp_b1[k];
#pragma unroll
            for (int p = 0; p < 32; ++p) v += h1part[p * 4096 + r * H1F + k];
            smem[tid] = v > 0.f ? v : 0.f;           // xin[8][32]
        }
        __syncthreads();
        const int c = tid;
        float acc[8] = {0, 0, 0, 0, 0, 0, 0, 0};
        const float* Wp = ncp_w2 + (size_t)kbeg * H2F + c;
#pragma unroll 8
        for (int kk = 0; kk < 32; ++kk) {
            float w = Wp[(size_t)kk * H2F];
#pragma unroll
            for (int r = 0; r < 8; ++r) acc[r] += smem[r * 32 + kk] * w;
        }
        float* outp = h2part + b * 2048;
#pragma unroll
        for (int r = 0; r < 8; ++r) outp[r * H2F + c] = acc[r];
    }
    grid.sync();

    // ======================= Stage C: L3 =======================
    if (b < 32) {
        const int kc = b >> 3;
        const int cbase = (b & 7) * 256;
        const int kbeg = kc * 64;
        for (int idx = tid; idx < 512; idx += 256) {
            int r = idx >> 6, kk = idx & 63;
            int k = kbeg + kk;
            float v = ncp_b2[k];
#pragma unroll
            for (int p = 0; p < 16; ++p) v += h2part[p * 2048 + r * H2F + k];
            smem[idx] = v > 0.f ? v : 0.f;           // xin[8][64]
        }
        __syncthreads();
        const int c = cbase + tid;
        float acc[8] = {0, 0, 0, 0, 0, 0, 0, 0};
        const float* Wp = ncp_w3 + (size_t)kbeg * NODE + c;
#pragma unroll 4
        for (int kk = 0; kk < 64; ++kk) {
            float w = Wp[(size_t)kk * NODE];
#pragma unroll
            for (int r = 0; r < 8; ++r) acc[r] += smem[r * 64 + kk] * w;
        }
        float* outp = xpart + kc * 16384;
#pragma unroll
        for (int r = 0; r < 8; ++r) outp[r * NODE + c] = acc[r];
    }
    grid.sync();

    // ======================= Stage D: Y2 (+ dot products) =======================
    {
        const int t = b >> 1;
        const int half = b & 1;
        float* shx = smem;            // [8][1024]
        float* redbuf = smem + 8192;  // [4][32]
        for (int i = tid; i < 8192; i += 256) {
            int r = i >> 10, cl = i & 1023;
            int c = half * 1024 + cl;
            float v = ncp_b3[c];
#pragma unroll
            for (int p = 0; p < 4; ++p) v += xpart[p * 16384 + r * NODE + c];
            shx[i] = 1.f / (1.f + expf(-v));
        }
        __syncthreads();

        float part[8] = {0, 0, 0, 0, 0, 0, 0, 0};
        const float* row = pr_w2 + (size_t)t * 8192 + half * 4096;
#pragma unroll 4
        for (int it = 0; it < 16; ++it) {
            int j = tid + it * 256;        // o = j&3 = tid&3 (fixed)
            float w = row[j];
            int cl = j >> 2;
#pragma unroll
            for (int s = 0; s < 8; ++s) part[s] += shx[s * 1024 + cl] * w;
        }
#pragma unroll
        for (int s = 0; s < 8; ++s) {
            part[s] += __shfl_xor(part[s], 4);
            part[s] += __shfl_xor(part[s], 8);
            part[s] += __shfl_xor(part[s], 16);
            part[s] += __shfl_xor(part[s], 32);
        }
        if (lane < 4) {
#pragma unroll
            for (int s = 0; s < 8; ++s) redbuf[wave * 32 + s * 4 + lane] = part[s];
        }
        __syncthreads();
        if (tid < 32) {
            float v = redbuf[tid] + redbuf[32 + tid] + redbuf[64 + tid] + redbuf[96 + tid];
            int s = tid >> 2, o = tid & 3;
            y2part[half * 4096 + (s * 128 + t) * 4 + o] = v;
        }

        // extra work on the two t==0 blocks: dotb/xr for this half
        if (t == 0) {
#pragma unroll
            for (int si = 0; si < 2; ++si) {
                const int s = wave * 2 + si;
                float pd[4] = {0, 0, 0, 0}, pr[4] = {0, 0, 0, 0};
#pragma unroll 4
                for (int it = 0; it < 16; ++it) {
                    int cl = it * 64 + lane;
                    float xv = shx[s * 1024 + cl];
                    int c = half * 1024 + cl;
                    float4 bv = ((const float4*)pr_b2)[c];
                    float4 rv = ((const float4*)root)[c];
                    pd[0] += xv * bv.x; pd[1] += xv * bv.y;
                    pd[2] += xv * bv.z; pd[3] += xv * bv.w;
                    pr[0] += xv * rv.x; pr[1] += xv * rv.y;
                    pr[2] += xv * rv.z; pr[3] += xv * rv.w;
                }
#pragma unroll
                for (int o = 0; o < 4; ++o) {
                    for (int off = 32; off; off >>= 1) {
                        pd[o] += __shfl_xor(pd[o], off);
                        pr[o] += __shfl_xor(pr[o], off);
                    }
                }
                if (lane == 0) {
#pragma unroll
                    for (int o = 0; o < 4; ++o) {
                        dotxr[half * 32 + s * 4 + o] = pd[o];
                        dotxr[64 + half * 32 + s * 4 + o] = pr[o];
                    }
                }
            }
        }
    }
    grid.sync();

    // ======================= Stage E: final combine (block 0) =======================
    if (b == 0) {
        float* sagg = smem;   // [8][4]
        if (tid < 32) sagg[tid] = 0.f;
        __syncthreads();

        const float* y2a = y2part;
        const float* y2b = y2part + 4096;
        for (int e = wave; e < 56; e += 4) {
            int i = e / 7, jj = e % 7;
            int dst = jj + (jj >= i ? 1 : 0);
            int src = i;
            float pm[4] = {0, 0, 0, 0};
#pragma unroll
            for (int half = 0; half < 2; ++half) {
                int t = lane + half * 64;
                float w = ewbuf[e * 128 + t];
                float4 ya = ((const float4*)y2a)[src * 128 + t];
                float4 yb = ((const float4*)y2b)[src * 128 + t];
                pm[0] += w * (ya.x + yb.x); pm[1] += w * (ya.y + yb.y);
                pm[2] += w * (ya.z + yb.z); pm[3] += w * (ya.w + yb.w);
            }
#pragma unroll
            for (int o = 0; o < 4; ++o)
                for (int off = 32; off; off >>= 1) pm[o] += __shfl_xor(pm[o], off);
            if (lane == 0) {
#pragma unroll
                for (int o = 0; o < 4; ++o) atomicAdd(&sagg[dst * 4 + o], pm[o]);
            }
        }
        __syncthreads();

        if (tid < 32) {
            int n = tid >> 2, o = tid & 3;
            float totd = 0.f;
#pragma unroll
            for (int s = 0; s < 8; ++s)
                totd += dotxr[s * 4 + o] + dotxr[32 + s * 4 + o];
            float dn = dotxr[n * 4 + o] + dotxr[32 + n * 4 + o];
            float xr = dotxr[64 + n * 4 + o] + dotxr[96 + n * 4 + o];
            out[tid] = sagg[tid] + (totd - dn) + xr + bias[o];
        }
    }
}

// ---------------------------------------------------------------------------
extern "C" void kernel_launch(void* const* d_in, const int* in_sizes, int n_in,
                              void* d_out, int out_size, void* d_ws, size_t ws_size,
                              hipStream_t stream)
{
    (void)in_sizes; (void)n_in; (void)out_size; (void)ws_size;

    const float* roi    = (const float*)d_in[0];   // [B,8,1024] -> batch 0 only
    const float* bbox   = (const float*)d_in[1];
    const float* dirs   = (const float*)d_in[2];
    const float* pri    = (const float*)d_in[3];
    const float* ncp_w1 = (const float*)d_in[4];
    const float* ncp_b1 = (const float*)d_in[5];
    const float* ncp_w2 = (const float*)d_in[6];
    const float* ncp_b2 = (const float*)d_in[7];
    const float* ncp_w3 = (const float*)d_in[8];
    const float* ncp_b3 = (const float*)d_in[9];
    const float* ep_w1  = (const float*)d_in[10];
    const float* ep_b1  = (const float*)d_in[11];
    const float* ep_w2  = (const float*)d_in[12];
    const float* ep_b2  = (const float*)d_in[13];
    const float* ep_w3  = (const float*)d_in[14];
    const float* ep_b3  = (const float*)d_in[15];
    const float* pr_w1  = (const float*)d_in[16];
    const float* pr_b1  = (const float*)d_in[17];
    const float* pr_w2  = (const float*)d_in[18];
    const float* pr_b2  = (const float*)d_in[19];
    const float* root   = (const float*)d_in[20];
    const float* bias   = (const float*)d_in[21];

    float* ws     = (float*)d_ws;
    float* h1part = ws + OFF_H1P;
    float* h2part = ws + OFF_H2P;
    float* xpart  = ws + OFF_XP;
    float* y2part = ws + OFF_Y2P;
    float* ewbuf  = ws + OFF_EW;
    float* dotxr  = ws + OFF_DX;
    float* outp   = (float*)d_out;

    void* args[] = {
        (void*)&roi, (void*)&bbox, (void*)&dirs, (void*)&pri,
        (void*)&ncp_w1, (void*)&ncp_b1, (void*)&ncp_w2, (void*)&ncp_b2,
        (void*)&ncp_w3, (void*)&ncp_b3,
        (void*)&ep_w1, (void*)&ep_b1, (void*)&ep_w2, (void*)&ep_b2,
        (void*)&ep_w3, (void*)&ep_b3,
        (void*)&pr_w1, (void*)&pr_b1, (void*)&pr_w2, (void*)&pr_b2,
        (void*)&root, (void*)&bias,
        (void*)&h1part, (void*)&h2part, (void*)&xpart, (void*)&y2part,
        (void*)&ewbuf, (void*)&dotxr, (void*)&outp
    };

    hipLaunchCooperativeKernel((void*)coop_all, dim3(256), dim3(256),
                               args, 0, stream);
}

// Round 4
// 276.333 us; speedup vs baseline: 1.4039x; 1.4039x over previous
//
#include <hip/hip_runtime.h>
#include <math.h>

// Problem constants
#define CIMG  1024
#define H1F   512
#define H2F   256
#define NODE  2048

// Workspace layout (float offsets) — every element written before read.
#define OFF_H1P  0        // h1part [16][8][512] = 65536
#define OFF_X    65536    // x      [8][2048]    = 16384
#define OFF_EW   81920    // ew     [56][128]    = 7168

// ---------------------------------------------------------------------------
// K1: blocks 0..31: L1 split-K partials (kc=b>>1 over 16 chunks of K=64,
//     cc=b&1 over 2 column groups of 256).  Block 32: full edge path -> ew,
//     plus zeroing d_out (consumed only by K3 atomics, after kernel boundary).
// ---------------------------------------------------------------------------
__global__ __launch_bounds__(256) void k1_l1_edge(
    const float* __restrict__ roi, const float* __restrict__ w1,
    const float* __restrict__ bbox, const float* __restrict__ dir,
    const float* __restrict__ pri,
    const float* __restrict__ ew1, const float* __restrict__ eb1,
    const float* __restrict__ ew2, const float* __restrict__ eb2,
    const float* __restrict__ ew3, const float* __restrict__ eb3,
    const float* __restrict__ pw1, const float* __restrict__ pb1,
    float* __restrict__ h1part, float* __restrict__ ew_out,
    float* __restrict__ out)
{
    __shared__ float smem[2848];
    const int tid = threadIdx.x;
    const int b = blockIdx.x;

    if (b < 32) {
        float* xin = smem;                    // [8][64]
        const int kbeg = (b >> 1) * 64;
        const int cbase = (b & 1) * 256;
        for (int idx = tid; idx < 512; idx += 256) {
            int r = idx >> 6, kk = idx & 63;
            xin[idx] = roi[r * CIMG + kbeg + kk];
        }
        __syncthreads();
        const int c = cbase + tid;
        float acc[8] = {0, 0, 0, 0, 0, 0, 0, 0};
        const float* Wp = w1 + (size_t)kbeg * H1F + c;
#pragma unroll 4
        for (int kk = 0; kk < 64; ++kk) {
            float w = Wp[(size_t)kk * H1F];
#pragma unroll
            for (int r = 0; r < 8; ++r) acc[r] += xin[r * 64 + kk] * w;
        }
        float* outp = h1part + (b >> 1) * 4096;
#pragma unroll
        for (int r = 0; r < 8; ++r) outp[r * H1F + c] = acc[r];
        return;
    }

    // ---- edge path (block 32) ----
    if (tid < 32) out[tid] = 0.f;   // zero-init output for K3's atomics

    float* attr = smem;            // [8][8]   = 64
    float* g1   = smem + 64;       // [8][256] = 2048
    float* g2   = smem + 2112;     // [8][64]  = 512
    float* ebuf = smem + 2624;     // [56][4]  = 224

    if (tid < 64) {
        int r = tid >> 3, j = tid & 7;
        attr[r * 8 + j] = (j < 4) ? bbox[r * 4 + j] * (1.0f / 1024.0f)
                                  : dir[r * 4 + (j - 4)];
    }
    __syncthreads();
    {
        int cc = tid;
        for (int r = 0; r < 8; ++r) {
            float s = eb1[cc];
#pragma unroll
            for (int j = 0; j < 8; ++j) s += attr[r * 8 + j] * ew1[j * 256 + cc];
            g1[r * 256 + cc] = s > 0.f ? s : 0.f;
        }
    }
    __syncthreads();
    for (int idx = tid; idx < 512; idx += 256) {
        int r = idx >> 6, cc = idx & 63;
        float s = eb2[cc];
        for (int j = 0; j < 256; ++j) s += g1[r * 256 + j] * ew2[j * 64 + cc];
        g2[idx] = s > 0.f ? s : 0.f;
    }
    __syncthreads();
    if (tid < 168) {   // g3 flat [8*21] == e channels 0..2 flat [56*3]
        int r = tid / 21, q = tid % 21;
        float s = eb3[q];
        for (int j = 0; j < 64; ++j) s += g2[r * 64 + j] * ew3[j * 21 + q];
        ebuf[(tid / 3) * 4 + (tid % 3)] = 1.f / (1.f + expf(-s));
    }
    if (tid < 56) {    // HigherPri quirk: pri[e/7] > pri[e%7]
        ebuf[tid * 4 + 3] = (pri[tid / 7] > pri[tid % 7]) ? 1.f : 0.f;
    }
    __syncthreads();
    for (int idx = tid; idx < 56 * 128; idx += 256) {
        int e = idx >> 7, t = idx & 127;
        float s = pb1[t];
#pragma unroll
        for (int ch = 0; ch < 4; ++ch) s += ebuf[e * 4 + ch] * pw1[ch * 128 + t];
        ew_out[idx] = s > 0.f ? s : 0.f;
    }
}

// ---------------------------------------------------------------------------
// K2: fused L2+L3. 16 blocks x 1024 threads. Each block:
//   stage1: h1[8][512] = relu(b1 + sum of 16 h1 partials)        (LDS)
//   stage2: h2 partials, K=512 split 4-way (kg=tid>>8, c=tid&255) (LDS)
//           h2[8][256] = relu(b2 + sum of 4 partials)
//   stage3: its 128-column slice of x = sigmoid(b3 + h2 @ w3)    (global)
// ---------------------------------------------------------------------------
__global__ __launch_bounds__(1024) void k2_l23(
    const float* __restrict__ h1part, const float* __restrict__ b1,
    const float* __restrict__ w2, const float* __restrict__ b2,
    const float* __restrict__ w3, const float* __restrict__ b3,
    float* __restrict__ x)
{
    __shared__ float h1[4096];     // [8][512]
    __shared__ float h2p[8192];    // [4][8][256]
    __shared__ float h2[2048];     // [8][256]
    const int tid = threadIdx.x;

    // stage 1
    for (int idx = tid; idx < 4096; idx += 1024) {
        int k = idx & 511;
        float v = b1[k];
#pragma unroll
        for (int p = 0; p < 16; ++p) v += h1part[p * 4096 + idx];
        h1[idx] = v > 0.f ? v : 0.f;
    }
    __syncthreads();

    // stage 2: 4-way K split
    {
        const int c = tid & 255, kg = tid >> 8;     // kg in 0..3, 128 k's each
        float acc[8] = {0, 0, 0, 0, 0, 0, 0, 0};
        const float* Wp = w2 + (size_t)(kg * 128) * H2F + c;
        const float* h1p = h1 + kg * 128;
#pragma unroll 4
        for (int kk = 0; kk < 128; ++kk) {
            float w = Wp[(size_t)kk * H2F];
#pragma unroll
            for (int r = 0; r < 8; ++r) acc[r] += h1p[r * 512 + kk] * w;
        }
#pragma unroll
        for (int r = 0; r < 8; ++r) h2p[kg * 2048 + r * 256 + c] = acc[r];
    }
    __syncthreads();
    for (int idx = tid; idx < 2048; idx += 1024) {
        int c = idx & 255;
        float v = b2[c] + h2p[idx] + h2p[2048 + idx] + h2p[4096 + idx] + h2p[6144 + idx];
        h2[idx] = v > 0.f ? v : 0.f;
    }
    __syncthreads();

    // stage 3: cols [blockIdx.x*128, +128), one (r,c) output per thread
    {
        const int c = blockIdx.x * 128 + (tid & 127);
        const int r = tid >> 7;                      // 0..7
        float acc = b3[c];
        const float* Wp = w3 + c;
        const float* h2r = h2 + r * 256;
#pragma unroll 4
        for (int k = 0; k < 256; ++k)
            acc += h2r[k] * Wp[(size_t)k * NODE];
        x[r * NODE + c] = 1.f / (1.f + expf(-acc));
    }
}

// ---------------------------------------------------------------------------
// K3: Y2 + final, 256 blocks (t=b>>1, half=b&1) x 256 threads.
//   Stage x-half into LDS; per-block Y2 reduction for its t; scatter edge
//   messages straight into out via atomics. t==0 blocks add dotb/xr/bias.
// ---------------------------------------------------------------------------
__global__ __launch_bounds__(256) void k3_y2_final(
    const float* __restrict__ x, const float* __restrict__ pw2,
    const float* __restrict__ pb2, const float* __restrict__ root,
    const float* __restrict__ bias, const float* __restrict__ ew,
    float* __restrict__ out)
{
    __shared__ float shx[8192];    // [8][1024]
    __shared__ float redbuf[128];
    __shared__ float ylocal[32];   // [8][4]
    __shared__ float aggl[32];     // [8][4]
    __shared__ float dotl[32], xrl[32];
    const int t = blockIdx.x >> 1;
    const int half = blockIdx.x & 1;
    const int tid = threadIdx.x;
    const int lane = tid & 63, wave = tid >> 6;

    if (tid < 32) aggl[tid] = 0.f;
    for (int i = tid; i < 8192; i += 256) {
        int r = i >> 10, cl = i & 1023;
        shx[i] = x[r * NODE + half * 1024 + cl];
    }
    __syncthreads();

    // Y2 reduction for this (t, half)
    float part[8] = {0, 0, 0, 0, 0, 0, 0, 0};
    const float* row = pw2 + (size_t)t * 8192 + half * 4096;
#pragma unroll 4
    for (int it = 0; it < 16; ++it) {
        int j = tid + it * 256;        // o = j&3 = tid&3 (fixed per thread)
        float w = row[j];
        int cl = j >> 2;
#pragma unroll
        for (int s = 0; s < 8; ++s) part[s] += shx[s * 1024 + cl] * w;
    }
#pragma unroll
    for (int s = 0; s < 8; ++s) {
        part[s] += __shfl_xor(part[s], 4);
        part[s] += __shfl_xor(part[s], 8);
        part[s] += __shfl_xor(part[s], 16);
        part[s] += __shfl_xor(part[s], 32);
    }
    if (lane < 4) {
#pragma unroll
        for (int s = 0; s < 8; ++s) redbuf[wave * 32 + s * 4 + lane] = part[s];
    }
    __syncthreads();
    if (tid < 32)
        ylocal[tid] = redbuf[tid] + redbuf[32 + tid] + redbuf[64 + tid] + redbuf[96 + tid];
    __syncthreads();

    // edge-message scatter for this t: 224 threads = (e, o)
    if (tid < 224) {
        int e = tid >> 2, o = tid & 3;
        int i = e / 7, jj = e % 7;
        int dst = jj + (jj >= i ? 1 : 0);
        float v = ew[e * 128 + t] * ylocal[i * 4 + o];
        atomicAdd(&aggl[dst * 4 + o], v);
    }
    __syncthreads();
    if (tid < 32) atomicAdd(&out[tid], aggl[tid]);

    // dotb / xr / bias on the two t==0 blocks
    if (t == 0) {
#pragma unroll
        for (int si = 0; si < 2; ++si) {
            const int s = wave * 2 + si;
            float pd[4] = {0, 0, 0, 0}, pr[4] = {0, 0, 0, 0};
#pragma unroll 4
            for (int it = 0; it < 16; ++it) {
                int cl = it * 64 + lane;
                float xv = shx[s * 1024 + cl];
                int c = half * 1024 + cl;
                float4 bv = ((const float4*)pb2)[c];
                float4 rv = ((const float4*)root)[c];
                pd[0] += xv * bv.x; pd[1] += xv * bv.y;
                pd[2] += xv * bv.z; pd[3] += xv * bv.w;
                pr[0] += xv * rv.x; pr[1] += xv * rv.y;
                pr[2] += xv * rv.z; pr[3] += xv * rv.w;
            }
#pragma unroll
            for (int o = 0; o < 4; ++o) {
                for (int off = 32; off; off >>= 1) {
                    pd[o] += __shfl_xor(pd[o], off);
                    pr[o] += __shfl_xor(pr[o], off);
                }
            }
            if (lane == 0) {
#pragma unroll
                for (int o = 0; o < 4; ++o) {
                    dotl[s * 4 + o] = pd[o];
                    xrl[s * 4 + o] = pr[o];
                }
            }
        }
        __syncthreads();
        if (tid < 32) {
            int n = tid >> 2, o = tid & 3;
            float totd = 0.f;
#pragma unroll
            for (int s = 0; s < 8; ++s) totd += dotl[s * 4 + o];
            float v = (totd - dotl[n * 4 + o]) + xrl[n * 4 + o]
                    + (half == 0 ? bias[o] : 0.f);
            atomicAdd(&out[tid], v);
        }
    }
}

// ---------------------------------------------------------------------------
extern "C" void kernel_launch(void* const* d_in, const int* in_sizes, int n_in,
                              void* d_out, int out_size, void* d_ws, size_t ws_size,
                              hipStream_t stream)
{
    (void)in_sizes; (void)n_in; (void)out_size; (void)ws_size;

    const float* roi    = (const float*)d_in[0];   // [B,8,1024] -> batch 0 only
    const float* bbox   = (const float*)d_in[1];
    const float* dirs   = (const float*)d_in[2];
    const float* pri    = (const float*)d_in[3];
    const float* ncp_w1 = (const float*)d_in[4];
    const float* ncp_b1 = (const float*)d_in[5];
    const float* ncp_w2 = (const float*)d_in[6];
    const float* ncp_b2 = (const float*)d_in[7];
    const float* ncp_w3 = (const float*)d_in[8];
    const float* ncp_b3 = (const float*)d_in[9];
    const float* ep_w1  = (const float*)d_in[10];
    const float* ep_b1  = (const float*)d_in[11];
    const float* ep_w2  = (const float*)d_in[12];
    const float* ep_b2  = (const float*)d_in[13];
    const float* ep_w3  = (const float*)d_in[14];
    const float* ep_b3  = (const float*)d_in[15];
    const float* pr_w1  = (const float*)d_in[16];
    const float* pr_b1  = (const float*)d_in[17];
    const float* pr_w2  = (const float*)d_in[18];
    const float* pr_b2  = (const float*)d_in[19];
    const float* root   = (const float*)d_in[20];
    const float* bias   = (const float*)d_in[21];

    float* ws     = (float*)d_ws;
    float* h1part = ws + OFF_H1P;
    float* x      = ws + OFF_X;
    float* ewbuf  = ws + OFF_EW;
    float* outp   = (float*)d_out;

    k1_l1_edge<<<33, dim3(256), 0, stream>>>(roi, ncp_w1, bbox, dirs, pri,
                                             ep_w1, ep_b1, ep_w2, ep_b2,
                                             ep_w3, ep_b3, pr_w1, pr_b1,
                                             h1part, ewbuf, outp);
    k2_l23<<<16, dim3(1024), 0, stream>>>(h1part, ncp_b1, ncp_w2, ncp_b2,
                                          ncp_w3, ncp_b3, x);
    k3_y2_final<<<256, dim3(256), 0, stream>>>(x, pr_w2, pr_b2, root, bias,
                                               ewbuf, outp);
}

// Round 5
// 246.921 us; speedup vs baseline: 1.5711x; 1.1191x over previous
//
#include <hip/hip_runtime.h>
#include <math.h>

// Problem constants
#define CIMG  1024
#define H1F   512
#define H2F   256
#define NODE  2048

// Workspace layout (float offsets) — every element written before read.
#define OFF_H1P  0        // h1part [32][8][512]  = 131072
#define OFF_H2P  131072   // h2part [16][8][256]  = 32768
#define OFF_XP   163840   // xpart  [4][8][2048]  = 65536
#define OFF_EW   229376   // ew     [56][128]     = 7168

// ---------------------------------------------------------------------------
// K1: blocks 0..63: L1 split-K partials (kc=b>>1 over 32 chunks of K=32,
//     cc=b&1 over 2 column groups of 256).  Block 64: edge path -> ew,
//     plus zeroing d_out (consumed by K4's atomics after kernel boundary).
// ---------------------------------------------------------------------------
__global__ __launch_bounds__(256) void k1_l1_edge(
    const float* __restrict__ roi, const float* __restrict__ w1,
    const float* __restrict__ bbox, const float* __restrict__ dir,
    const float* __restrict__ pri,
    const float* __restrict__ ew1, const float* __restrict__ eb1,
    const float* __restrict__ ew2, const float* __restrict__ eb2,
    const float* __restrict__ ew3, const float* __restrict__ eb3,
    const float* __restrict__ pw1, const float* __restrict__ pb1,
    float* __restrict__ h1part, float* __restrict__ ew_out,
    float* __restrict__ out)
{
    __shared__ float smem[2848];
    const int tid = threadIdx.x;
    const int b = blockIdx.x;

    if (b < 64) {
        float* xin = smem;                    // [8][32]
        const int kc = b >> 1;
        const int kbeg = kc * 32;
        const int cbase = (b & 1) * 256;
        {
            int r = tid >> 5, kk = tid & 31;
            xin[tid] = roi[r * CIMG + kbeg + kk];
        }
        __syncthreads();
        const int c = cbase + tid;
        float acc[8] = {0, 0, 0, 0, 0, 0, 0, 0};
        const float* Wp = w1 + (size_t)kbeg * H1F + c;
#pragma unroll
        for (int k4 = 0; k4 < 8; ++k4) {
            float wa = Wp[(size_t)(k4 * 4 + 0) * H1F];
            float wb = Wp[(size_t)(k4 * 4 + 1) * H1F];
            float wc = Wp[(size_t)(k4 * 4 + 2) * H1F];
            float wd = Wp[(size_t)(k4 * 4 + 3) * H1F];
#pragma unroll
            for (int r = 0; r < 8; ++r) {
                float4 xv = *(const float4*)&xin[r * 32 + k4 * 4];
                acc[r] += xv.x * wa + xv.y * wb + xv.z * wc + xv.w * wd;
            }
        }
        float* outp = h1part + kc * 4096;
#pragma unroll
        for (int r = 0; r < 8; ++r) outp[r * H1F + c] = acc[r];
        return;
    }

    // ---- edge path (block 64) ----
    if (tid < 32) out[tid] = 0.f;   // zero-init output for K4's atomics

    float* attr = smem;            // [8][8]   = 64
    float* g1   = smem + 64;       // [8][256] = 2048
    float* g2   = smem + 2112;     // [8][64]  = 512
    float* ebuf = smem + 2624;     // [56][4]  = 224

    if (tid < 64) {
        int r = tid >> 3, j = tid & 7;
        attr[r * 8 + j] = (j < 4) ? bbox[r * 4 + j] * (1.0f / 1024.0f)
                                  : dir[r * 4 + (j - 4)];
    }
    __syncthreads();
    {
        int cc = tid;
        for (int r = 0; r < 8; ++r) {
            float s = eb1[cc];
#pragma unroll
            for (int j = 0; j < 8; ++j) s += attr[r * 8 + j] * ew1[j * 256 + cc];
            g1[r * 256 + cc] = s > 0.f ? s : 0.f;
        }
    }
    __syncthreads();
    for (int idx = tid; idx < 512; idx += 256) {
        int r = idx >> 6, cc = idx & 63;
        float s = eb2[cc];
        for (int j = 0; j < 256; ++j) s += g1[r * 256 + j] * ew2[j * 64 + cc];
        g2[idx] = s > 0.f ? s : 0.f;
    }
    __syncthreads();
    if (tid < 168) {   // g3 flat [8*21] == e channels 0..2 flat [56*3]
        int r = tid / 21, q = tid % 21;
        float s = eb3[q];
        for (int j = 0; j < 64; ++j) s += g2[r * 64 + j] * ew3[j * 21 + q];
        ebuf[(tid / 3) * 4 + (tid % 3)] = 1.f / (1.f + expf(-s));
    }
    if (tid < 56) {    // HigherPri quirk: pri[e/7] > pri[e%7]
        ebuf[tid * 4 + 3] = (pri[tid / 7] > pri[tid % 7]) ? 1.f : 0.f;
    }
    __syncthreads();
    for (int idx = tid; idx < 56 * 128; idx += 256) {
        int e = idx >> 7, t = idx & 127;
        float s = pb1[t];
#pragma unroll
        for (int ch = 0; ch < 4; ++ch) s += ebuf[e * 4 + ch] * pw1[ch * 128 + t];
        ew_out[idx] = s > 0.f ? s : 0.f;
    }
}

// ---------------------------------------------------------------------------
// K2: L2. 16 blocks x 256. Stage relu(b1 + sum of 32 h1 partials) for this
// 32-k chunk into LDS, then one column per thread, float4 LDS reads.
// ---------------------------------------------------------------------------
__global__ __launch_bounds__(256) void k2_l2(
    const float* __restrict__ h1part, const float* __restrict__ b1,
    const float* __restrict__ w2, float* __restrict__ h2part)
{
    __shared__ float xin[256];     // [8][32]
    const int tid = threadIdx.x;
    const int kbeg = blockIdx.x * 32;

    {
        int r = tid >> 5, kk = tid & 31;
        int k = kbeg + kk;
        float v = b1[k];
#pragma unroll
        for (int p = 0; p < 32; ++p) v += h1part[p * 4096 + r * H1F + k];
        xin[tid] = v > 0.f ? v : 0.f;
    }
    __syncthreads();

    const int c = tid;
    float acc[8] = {0, 0, 0, 0, 0, 0, 0, 0};
    const float* Wp = w2 + (size_t)kbeg * H2F + c;
#pragma unroll
    for (int k4 = 0; k4 < 8; ++k4) {
        float wa = Wp[(size_t)(k4 * 4 + 0) * H2F];
        float wb = Wp[(size_t)(k4 * 4 + 1) * H2F];
        float wc = Wp[(size_t)(k4 * 4 + 2) * H2F];
        float wd = Wp[(size_t)(k4 * 4 + 3) * H2F];
#pragma unroll
        for (int r = 0; r < 8; ++r) {
            float4 xv = *(const float4*)&xin[r * 32 + k4 * 4];
            acc[r] += xv.x * wa + xv.y * wb + xv.z * wc + xv.w * wd;
        }
    }
    float* outp = h2part + blockIdx.x * 2048;
#pragma unroll
    for (int r = 0; r < 8; ++r) outp[r * H2F + c] = acc[r];
}

// ---------------------------------------------------------------------------
// K3: L3. 32 blocks = 4 kchunks(64) x 8 cchunks(256). Stage relu(b2 + sum of
// 16 h2 partials), write xpart[kc][8][2048] (pre-bias, pre-sigmoid).
// ---------------------------------------------------------------------------
__global__ __launch_bounds__(256) void k3_l3(
    const float* __restrict__ h2part, const float* __restrict__ b2,
    const float* __restrict__ w3, float* __restrict__ xpart)
{
    __shared__ float xin[512];     // [8][64]
    const int tid = threadIdx.x;
    const int kc = blockIdx.x >> 3;
    const int cbase = (blockIdx.x & 7) * 256;
    const int kbeg = kc * 64;

    for (int idx = tid; idx < 512; idx += 256) {
        int r = idx >> 6, kk = idx & 63;
        int k = kbeg + kk;
        float v = b2[k];
#pragma unroll
        for (int p = 0; p < 16; ++p) v += h2part[p * 2048 + r * H2F + k];
        xin[idx] = v > 0.f ? v : 0.f;
    }
    __syncthreads();

    const int c = cbase + tid;
    float acc[8] = {0, 0, 0, 0, 0, 0, 0, 0};
    const float* Wp = w3 + (size_t)kbeg * NODE + c;
#pragma unroll
    for (int k4 = 0; k4 < 16; ++k4) {
        float wa = Wp[(size_t)(k4 * 4 + 0) * NODE];
        float wb = Wp[(size_t)(k4 * 4 + 1) * NODE];
        float wc = Wp[(size_t)(k4 * 4 + 2) * NODE];
        float wd = Wp[(size_t)(k4 * 4 + 3) * NODE];
#pragma unroll
        for (int r = 0; r < 8; ++r) {
            float4 xv = *(const float4*)&xin[r * 64 + k4 * 4];
            acc[r] += xv.x * wa + xv.y * wb + xv.z * wc + xv.w * wd;
        }
    }
    float* outp = xpart + kc * 16384;
#pragma unroll
    for (int r = 0; r < 8; ++r) outp[r * NODE + c] = acc[r];
}

// ---------------------------------------------------------------------------
// K4: Y2 + final, 256 blocks (t=b>>1, half=b&1) x 256 threads.
//   Stage x-half = sigmoid(b3 + sum of 4 xparts) into LDS; per-block Y2
//   reduction for its t; scatter edge messages straight into out via atomics.
//   t==0 blocks add dotb/xr/bias terms.
// ---------------------------------------------------------------------------
__global__ __launch_bounds__(256) void k4_y2_final(
    const float* __restrict__ xpart, const float* __restrict__ b3,
    const float* __restrict__ pw2, const float* __restrict__ pb2,
    const float* __restrict__ root, const float* __restrict__ bias,
    const float* __restrict__ ew, float* __restrict__ out)
{
    __shared__ float shx[8192];    // [8][1024]
    __shared__ float redbuf[128];
    __shared__ float ylocal[32];   // [8][4]
    __shared__ float aggl[32];     // [8][4]
    __shared__ float dotl[32], xrl[32];
    const int t = blockIdx.x >> 1;
    const int half = blockIdx.x & 1;
    const int tid = threadIdx.x;
    const int lane = tid & 63, wave = tid >> 6;

    if (tid < 32) aggl[tid] = 0.f;
    for (int i = tid; i < 8192; i += 256) {
        int r = i >> 10, cl = i & 1023;
        int c = half * 1024 + cl;
        float v = b3[c];
#pragma unroll
        for (int p = 0; p < 4; ++p) v += xpart[p * 16384 + r * NODE + c];
        shx[i] = 1.f / (1.f + expf(-v));
    }
    __syncthreads();

    // Y2 reduction for this (t, half)
    float part[8] = {0, 0, 0, 0, 0, 0, 0, 0};
    const float* row = pw2 + (size_t)t * 8192 + half * 4096;
#pragma unroll 4
    for (int it = 0; it < 16; ++it) {
        int j = tid + it * 256;        // o = j&3 = tid&3 (fixed per thread)
        float w = row[j];
        int cl = j >> 2;
#pragma unroll
        for (int s = 0; s < 8; ++s) part[s] += shx[s * 1024 + cl] * w;
    }
#pragma unroll
    for (int s = 0; s < 8; ++s) {
        part[s] += __shfl_xor(part[s], 4);
        part[s] += __shfl_xor(part[s], 8);
        part[s] += __shfl_xor(part[s], 16);
        part[s] += __shfl_xor(part[s], 32);
    }
    if (lane < 4) {
#pragma unroll
        for (int s = 0; s < 8; ++s) redbuf[wave * 32 + s * 4 + lane] = part[s];
    }
    __syncthreads();
    if (tid < 32)
        ylocal[tid] = redbuf[tid] + redbuf[32 + tid] + redbuf[64 + tid] + redbuf[96 + tid];
    __syncthreads();

    // edge-message scatter for this t: 224 threads = (e, o)
    if (tid < 224) {
        int e = tid >> 2, o = tid & 3;
        int i = e / 7, jj = e % 7;
        int dst = jj + (jj >= i ? 1 : 0);
        float v = ew[e * 128 + t] * ylocal[i * 4 + o];
        atomicAdd(&aggl[dst * 4 + o], v);
    }
    __syncthreads();
    if (tid < 32) atomicAdd(&out[tid], aggl[tid]);

    // dotb / xr / bias on the two t==0 blocks
    if (t == 0) {
#pragma unroll
        for (int si = 0; si < 2; ++si) {
            const int s = wave * 2 + si;
            float pd[4] = {0, 0, 0, 0}, pr[4] = {0, 0, 0, 0};
#pragma unroll 4
            for (int it = 0; it < 16; ++it) {
                int cl = it * 64 + lane;
                float xv = shx[s * 1024 + cl];
                int c = half * 1024 + cl;
                float4 bv = ((const float4*)pb2)[c];
                float4 rv = ((const float4*)root)[c];
                pd[0] += xv * bv.x; pd[1] += xv * bv.y;
                pd[2] += xv * bv.z; pd[3] += xv * bv.w;
                pr[0] += xv * rv.x; pr[1] += xv * rv.y;
                pr[2] += xv * rv.z; pr[3] += xv * rv.w;
            }
#pragma unroll
            for (int o = 0; o < 4; ++o) {
                for (int off = 32; off; off >>= 1) {
                    pd[o] += __shfl_xor(pd[o], off);
                    pr[o] += __shfl_xor(pr[o], off);
                }
            }
            if (lane == 0) {
#pragma unroll
                for (int o = 0; o < 4; ++o) {
                    dotl[s * 4 + o] = pd[o];
                    xrl[s * 4 + o] = pr[o];
                }
            }
        }
        __syncthreads();
        if (tid < 32) {
            int n = tid >> 2, o = tid & 3;
            float totd = 0.f;
#pragma unroll
            for (int s = 0; s < 8; ++s) totd += dotl[s * 4 + o];
            float v = (totd - dotl[n * 4 + o]) + xrl[n * 4 + o]
                    + (half == 0 ? bias[o] : 0.f);
            atomicAdd(&out[tid], v);
        }
    }
}

// ---------------------------------------------------------------------------
extern "C" void kernel_launch(void* const* d_in, const int* in_sizes, int n_in,
                              void* d_out, int out_size, void* d_ws, size_t ws_size,
                              hipStream_t stream)
{
    (void)in_sizes; (void)n_in; (void)out_size; (void)ws_size;

    const float* roi    = (const float*)d_in[0];   // [B,8,1024] -> batch 0 only
    const float* bbox   = (const float*)d_in[1];
    const float* dirs   = (const float*)d_in[2];
    const float* pri    = (const float*)d_in[3];
    const float* ncp_w1 = (const float*)d_in[4];
    const float* ncp_b1 = (const float*)d_in[5];
    const float* ncp_w2 = (const float*)d_in[6];
    const float* ncp_b2 = (const float*)d_in[7];
    const float* ncp_w3 = (const float*)d_in[8];
    const float* ncp_b3 = (const float*)d_in[9];
    const float* ep_w1  = (const float*)d_in[10];
    const float* ep_b1  = (const float*)d_in[11];
    const float* ep_w2  = (const float*)d_in[12];
    const float* ep_b2  = (const float*)d_in[13];
    const float* ep_w3  = (const float*)d_in[14];
    const float* ep_b3  = (const float*)d_in[15];
    const float* pr_w1  = (const float*)d_in[16];
    const float* pr_b1  = (const float*)d_in[17];
    const float* pr_w2  = (const float*)d_in[18];
    const float* pr_b2  = (const float*)d_in[19];
    const float* root   = (const float*)d_in[20];
    const float* bias   = (const float*)d_in[21];

    float* ws     = (float*)d_ws;
    float* h1part = ws + OFF_H1P;
    float* h2part = ws + OFF_H2P;
    float* xpart  = ws + OFF_XP;
    float* ewbuf  = ws + OFF_EW;
    float* outp   = (float*)d_out;

    k1_l1_edge<<<65, dim3(256), 0, stream>>>(roi, ncp_w1, bbox, dirs, pri,
                                             ep_w1, ep_b1, ep_w2, ep_b2,
                                             ep_w3, ep_b3, pr_w1, pr_b1,
                                             h1part, ewbuf, outp);
    k2_l2<<<16, dim3(256), 0, stream>>>(h1part, ncp_b1, ncp_w2, h2part);
    k3_l3<<<32, dim3(256), 0, stream>>>(h2part, ncp_b2, ncp_w3, xpart);
    k4_y2_final<<<256, dim3(256), 0, stream>>>(xpart, ncp_b3, pr_w2, pr_b2,
                                               root, bias, ewbuf, outp);
}